// Round 1
// baseline (548.438 us; speedup 1.0000x reference)
//
#include <hip/hip_runtime.h>

#define B_ 4
#define T_ 1024
#define D_ 512
#define H_ 8
#define DH_ 64
#define L_ 2047

#define TQ 128
#define TJ 64
#define RWW 200   // R-window buffer width (192 used + pad)

// ---------------------------------------------------------------------------
// GEMM: C[M,N] = A[M,K] @ W[K,N] (+ bias). 64x64 tile, BK=32, 4x4 per thread.
// A staged transposed in LDS so both fragment reads are aligned b128.
// ---------------------------------------------------------------------------
__global__ __launch_bounds__(256)
void gemm_bias_kernel(const float* __restrict__ A, const float* __restrict__ W,
                      const float* __restrict__ bias, float* __restrict__ C,
                      int M, int N, int K) {
  __shared__ float AsT[32][68];   // [kk][row]
  __shared__ float Bs[32][68];    // [kk][col]
  const int tid = threadIdx.x;
  const int tx = tid & 15;
  const int ty = tid >> 4;
  const int row0 = blockIdx.x * 64;
  const int col0 = blockIdx.y * 64;

  float acc[4][4];
#pragma unroll
  for (int i = 0; i < 4; ++i)
#pragma unroll
    for (int j = 0; j < 4; ++j) acc[i][j] = 0.f;

  for (int k0 = 0; k0 < K; k0 += 32) {
    // A tile: 64 rows x 32 k -> 512 float4 slots, 2 per thread, store transposed
#pragma unroll
    for (int s = tid; s < 512; s += 256) {
      int r  = s >> 3;
      int c4 = (s & 7) << 2;
      int gr = row0 + r;
      float4 a;
      if (gr < M) a = *(const float4*)&A[gr * K + k0 + c4];
      else        a = make_float4(0.f, 0.f, 0.f, 0.f);
      AsT[c4 + 0][r] = a.x;
      AsT[c4 + 1][r] = a.y;
      AsT[c4 + 2][r] = a.z;
      AsT[c4 + 3][r] = a.w;
    }
    // B tile: 32 k x 64 cols, natural layout
#pragma unroll
    for (int s = tid; s < 512; s += 256) {
      int r  = s >> 4;
      int c4 = (s & 15) << 2;
      *(float4*)&Bs[r][c4] = *(const float4*)&W[(k0 + r) * N + col0 + c4];
    }
    __syncthreads();
#pragma unroll
    for (int kk = 0; kk < 32; ++kk) {
      float4 a4 = *(const float4*)&AsT[kk][ty << 2];
      float4 b4 = *(const float4*)&Bs[kk][tx << 2];
      float av[4] = {a4.x, a4.y, a4.z, a4.w};
      float bv[4] = {b4.x, b4.y, b4.z, b4.w};
#pragma unroll
      for (int i = 0; i < 4; ++i)
#pragma unroll
        for (int j = 0; j < 4; ++j)
          acc[i][j] = fmaf(av[i], bv[j], acc[i][j]);
    }
    __syncthreads();
  }

#pragma unroll
  for (int i = 0; i < 4; ++i) {
    int row = row0 + (ty << 2) + i;
    if (row < M) {
      int col = col0 + (tx << 2);
      float bx = 0.f, by = 0.f, bz = 0.f, bw = 0.f;
      if (bias) { bx = bias[col]; by = bias[col + 1]; bz = bias[col + 2]; bw = bias[col + 3]; }
      float4 o;
      o.x = acc[i][0] + bx;
      o.y = acc[i][1] + by;
      o.z = acc[i][2] + bz;
      o.w = acc[i][3] + bw;
      *(float4*)&C[row * N + col] = o;
    }
  }
}

// ---------------------------------------------------------------------------
// Fused relative-position attention (Transformer-XL style), flash-style
// online softmax. One block = (q-tile of 128 rows, head h, batch b).
// rel_shift folded into indexing: score(q,j) uses r row  g = j + (T-1) - q.
// ---------------------------------------------------------------------------
__global__ __launch_bounds__(512)
void attn_fused_kernel(const float* __restrict__ qm, const float* __restrict__ km,
                       const float* __restrict__ vm, const float* __restrict__ rm,
                       const float* __restrict__ ub, const float* __restrict__ vb,
                       float* __restrict__ om) {
  const int qt = blockIdx.x;   // 0..7
  const int h  = blockIdx.y;   // 0..7
  const int b  = blockIdx.z;   // 0..3
  const int q0 = qt * TQ;
  const int tid = threadIdx.x; // 0..511
  const int tx = tid & 15;     // j / d groups
  const int ty = tid >> 4;     // 0..31, q-row groups

  __shared__ float QuT[64][TQ + 4];   // [d][qi]  (q + u)
  __shared__ float RW[64][RWW];       // [d][g]   r window (transposed)
  __shared__ float KT[64][TJ + 4];    // [d][ji]
  __shared__ float Vs[TJ][DH_ + 4];   // [ji][d]
  __shared__ float dvu[64];           // v_bias - u_bias for this head
  float (*PT)[TQ + 4] = (float (*)[TQ + 4])&RW[0][0];  // alias: P transposed [ji][qi]

  if (tid < 64) dvu[tid] = vb[h * DH_ + tid] - ub[h * DH_ + tid];

  // stage Qu = q + u, transposed: 128*64 floats = 2048 float4, 4 per thread
#pragma unroll
  for (int s = tid; s < TQ * 16; s += 512) {
    int qi = s >> 4;
    int d4 = (s & 15) << 2;
    float4 a  = *(const float4*)&qm[(b * T_ + q0 + qi) * D_ + h * DH_ + d4];
    float4 uu = *(const float4*)&ub[h * DH_ + d4];
    QuT[d4 + 0][qi] = a.x + uu.x;
    QuT[d4 + 1][qi] = a.y + uu.y;
    QuT[d4 + 2][qi] = a.z + uu.z;
    QuT[d4 + 3][qi] = a.w + uu.w;
  }

  float acc[4][4];
#pragma unroll
  for (int i = 0; i < 4; ++i)
#pragma unroll
    for (int j = 0; j < 4; ++j) acc[i][j] = 0.f;
  float m_run[4], l_run[4];
#pragma unroll
  for (int i = 0; i < 4; ++i) { m_run[i] = -3.0e38f; l_run[i] = 0.f; }

  for (int j0 = 0; j0 < T_; j0 += TJ) {
    __syncthreads();  // covers Qu staging (iter 0) and prev-iter PT/Vs reads

    // stage K tile transposed
#pragma unroll
    for (int s = tid; s < TJ * 16; s += 512) {
      int ji = s >> 4;
      int d4 = (s & 15) << 2;
      float4 a = *(const float4*)&km[(b * T_ + j0 + ji) * D_ + h * DH_ + d4];
      KT[d4 + 0][ji] = a.x;
      KT[d4 + 1][ji] = a.y;
      KT[d4 + 2][ji] = a.z;
      KT[d4 + 3][ji] = a.w;
    }
    // stage V tile natural layout
#pragma unroll
    for (int s = tid; s < TJ * 16; s += 512) {
      int ji = s >> 4;
      int d4 = (s & 15) << 2;
      *(float4*)&Vs[ji][d4] = *(const float4*)&vm[(b * T_ + j0 + ji) * D_ + h * DH_ + d4];
    }
    // stage R window transposed: rows w0+g, g in [0,191]
    const int w0 = j0 - q0 + (T_ - 1) - (TQ - 1);
#pragma unroll
    for (int s = tid; s < 192 * 16; s += 512) {
      int g  = s >> 4;
      int d4 = (s & 15) << 2;
      int w  = w0 + g;
      w = min(max(w, 0), L_ - 1);   // g=191 is loaded-but-unused; clamp keeps it in-bounds
      float4 a = *(const float4*)&rm[w * D_ + h * DH_ + d4];
      RW[d4 + 0][g] = a.x;
      RW[d4 + 1][g] = a.y;
      RW[d4 + 2][g] = a.z;
      RW[d4 + 3][g] = a.w;
    }
    __syncthreads();

    // S tile: ac = (q+u)·k^T, bd = (q+v)·r_shifted^T
    float ac[4][4], bd[4][4];
#pragma unroll
    for (int i = 0; i < 4; ++i)
#pragma unroll
      for (int j = 0; j < 4; ++j) { ac[i][j] = 0.f; bd[i][j] = 0.f; }

    const int c0 = (TQ - 4) + 4 * tx - 4 * ty;   // window base for this thread
    for (int d = 0; d < 64; ++d) {
      float4 qu4 = *(const float4*)&QuT[d][ty << 2];
      float4 k4  = *(const float4*)&KT[d][tx << 2];
      float4 ra  = *(const float4*)&RW[d][c0];
      float4 rb  = *(const float4*)&RW[d][c0 + 4];
      float dv = dvu[d];
      float qa[4] = {qu4.x, qu4.y, qu4.z, qu4.w};
      float ka[4] = {k4.x, k4.y, k4.z, k4.w};
      float rt[8] = {ra.x, ra.y, ra.z, ra.w, rb.x, rb.y, rb.z, rb.w};
#pragma unroll
      for (int i = 0; i < 4; ++i) {
        float qv = qa[i] + dv;
#pragma unroll
        for (int j = 0; j < 4; ++j) {
          ac[i][j] = fmaf(qa[i], ka[j], ac[i][j]);
          bd[i][j] = fmaf(qv, rt[j - i + 3], bd[i][j]);
        }
      }
    }

    // scores + online softmax (rows = ty*4+i, 16 tx lanes share a row)
    float p[4][4];
#pragma unroll
    for (int i = 0; i < 4; ++i)
#pragma unroll
      for (int j = 0; j < 4; ++j)
        p[i][j] = (ac[i][j] + bd[i][j]) * 0.125f;

#pragma unroll
    for (int i = 0; i < 4; ++i) {
      float lm = fmaxf(fmaxf(p[i][0], p[i][1]), fmaxf(p[i][2], p[i][3]));
#pragma unroll
      for (int off = 1; off < 16; off <<= 1)
        lm = fmaxf(lm, __shfl_xor(lm, off, 64));
      float mnew = fmaxf(m_run[i], lm);
      float sc = __expf(m_run[i] - mnew);
      float srow = 0.f;
#pragma unroll
      for (int j = 0; j < 4; ++j) {
        p[i][j] = __expf(p[i][j] - mnew);
        srow += p[i][j];
      }
#pragma unroll
      for (int off = 1; off < 16; off <<= 1)
        srow += __shfl_xor(srow, off, 64);
      l_run[i] = l_run[i] * sc + srow;
      m_run[i] = mnew;
#pragma unroll
      for (int j = 0; j < 4; ++j) acc[i][j] *= sc;
    }

    __syncthreads();  // everyone done reading RW before PT (alias) is written
#pragma unroll
    for (int j = 0; j < 4; ++j)
#pragma unroll
      for (int i = 0; i < 4; ++i)
        PT[(tx << 2) + j][(ty << 2) + i] = p[i][j];
    __syncthreads();

    // PV accumulate: out[qi][d] += P[qi][ji] * V[ji][d]
    for (int ji = 0; ji < TJ; ++ji) {
      float4 p4 = *(const float4*)&PT[ji][ty << 2];
      float4 v4 = *(const float4*)&Vs[ji][tx << 2];
      float pa[4] = {p4.x, p4.y, p4.z, p4.w};
      float va[4] = {v4.x, v4.y, v4.z, v4.w};
#pragma unroll
      for (int i = 0; i < 4; ++i)
#pragma unroll
        for (int j = 0; j < 4; ++j)
          acc[i][j] = fmaf(pa[i], va[j], acc[i][j]);
    }
  }

  // epilogue: normalize and store [B,T,H,DH]
#pragma unroll
  for (int i = 0; i < 4; ++i) {
    float inv = 1.f / l_run[i];
    float4 o;
    o.x = acc[i][0] * inv;
    o.y = acc[i][1] * inv;
    o.z = acc[i][2] * inv;
    o.w = acc[i][3] * inv;
    *(float4*)&om[(b * T_ + q0 + (ty << 2) + i) * D_ + h * DH_ + (tx << 2)] = o;
  }
}

// ---------------------------------------------------------------------------
extern "C" void kernel_launch(void* const* d_in, const int* in_sizes, int n_in,
                              void* d_out, int out_size, void* d_ws, size_t ws_size,
                              hipStream_t stream) {
  const float* x       = (const float*)d_in[0];
  const float* pos_emb = (const float*)d_in[1];
  const float* Wq      = (const float*)d_in[2];
  const float* bq      = (const float*)d_in[3];
  const float* Wk      = (const float*)d_in[4];
  const float* bk      = (const float*)d_in[5];
  const float* Wv      = (const float*)d_in[6];
  const float* bv      = (const float*)d_in[7];
  const float* Wr      = (const float*)d_in[8];
  const float* Wo      = (const float*)d_in[9];
  const float* bo      = (const float*)d_in[10];
  const float* u       = (const float*)d_in[11];
  const float* v       = (const float*)d_in[12];
  // d_in[13]/d_in[14] = ln_gamma / ln_beta: dead code in the reference.

  float* out = (float*)d_out;
  float* ws  = (float*)d_ws;

  const int MT = B_ * T_;          // 4096
  float* q   = ws;                 // [4096,512]
  float* k   = q  + MT * D_;       // [4096,512]
  float* vv  = k  + MT * D_;       // [4096,512]
  float* r   = vv + MT * D_;       // [2047,512] (padded to 2048 rows)
  float* att = r  + 2048 * D_;     // [4096,512]

  gemm_bias_kernel<<<dim3(MT / 64, D_ / 64), 256, 0, stream>>>(x, Wq, bq, q, MT, D_, D_);
  gemm_bias_kernel<<<dim3(MT / 64, D_ / 64), 256, 0, stream>>>(x, Wk, bk, k, MT, D_, D_);
  gemm_bias_kernel<<<dim3(MT / 64, D_ / 64), 256, 0, stream>>>(x, Wv, bv, vv, MT, D_, D_);
  gemm_bias_kernel<<<dim3((L_ + 63) / 64, D_ / 64), 256, 0, stream>>>(pos_emb, Wr, nullptr, r, L_, D_, D_);
  attn_fused_kernel<<<dim3(T_ / TQ, H_, B_), 512, 0, stream>>>(q, k, vv, r, u, v, att);
  gemm_bias_kernel<<<dim3(MT / 64, D_ / 64), 256, 0, stream>>>(att, Wo, bo, out, MT, D_, D_);
}

// Round 2
// 398.879 us; speedup vs baseline: 1.3749x; 1.3749x over previous
//
#include <hip/hip_runtime.h>

#define B_ 4
#define T_ 1024
#define D_ 512
#define H_ 8
#define DH_ 64
#define L_ 2047

#define TQ 128
#define TJ 64

typedef __attribute__((ext_vector_type(8))) short bf16x8;
typedef __attribute__((ext_vector_type(4))) float f32x4;
typedef __attribute__((ext_vector_type(8))) unsigned short us8v;
typedef __attribute__((ext_vector_type(4))) unsigned short us4v;

__device__ __forceinline__ void split_bf16(float a, unsigned short& h, unsigned short& l) {
  unsigned u = __float_as_uint(a);
  h = (unsigned short)(u >> 16);
  float hf = __uint_as_float(u & 0xFFFF0000u);
  l = (unsigned short)(__float_as_uint(a - hf) >> 16);
}

// ---------------------------------------------------------------------------
// x -> (hi, lo) bf16 split, elementwise. 2048 blocks x 256 thr x 4 elems.
// ---------------------------------------------------------------------------
__global__ __launch_bounds__(256)
void convert_split(const float* __restrict__ in, unsigned short* __restrict__ hi,
                   unsigned short* __restrict__ lo) {
  int i = (blockIdx.x * 256 + threadIdx.x) * 4;
  float4 a = *(const float4*)&in[i];
  us4v h, l;
  unsigned short th, tl;
  split_bf16(a.x, th, tl); h[0] = th; l[0] = tl;
  split_bf16(a.y, th, tl); h[1] = th; l[1] = tl;
  split_bf16(a.z, th, tl); h[2] = th; l[2] = tl;
  split_bf16(a.w, th, tl); h[3] = th; l[3] = tl;
  *(us4v*)&hi[i] = h;
  *(us4v*)&lo[i] = l;
}

// ---------------------------------------------------------------------------
// Split-bf16 MFMA GEMM: C[M,512] = A[M,512] @ W[512,512] (+bias).
// BM=128, BN=64, BK=32, 256 thr = 4 waves (2x2), wave tile 64x32 (4x2 frags).
// 3 MFMAs per frag pair (hh, hl, lh) ~ fp32 precision.
// MODE 0: QKV fused over concatenated N=1536 (A pre-split = x).
// MODE 1: R (A = pos_emb fp32, split on the fly, M=2047 guarded).
// MODE 2: O (A pre-split = attn output).
// ---------------------------------------------------------------------------
template<int MODE>
__global__ __launch_bounds__(256)
void gemm_split(const unsigned short* __restrict__ Aph, const unsigned short* __restrict__ Apl,
                const float* __restrict__ Afp,
                const float* __restrict__ Wa, const float* __restrict__ Wb, const float* __restrict__ Wc,
                const float* __restrict__ ba, const float* __restrict__ bb, const float* __restrict__ bc,
                float* __restrict__ Ca, float* __restrict__ Cb, float* __restrict__ Cc) {
  __shared__ unsigned short Ah[128][40], Al[128][40];   // [row][k], stride 40 (16B-aligned rows)
  __shared__ unsigned short Bh[64][40],  Bl[64][40];    // [col][k] (transposed)

  const int tid = threadIdx.x;
  const int row0 = blockIdx.x * 128;
  const int cg0  = blockIdx.y * 64;

  const float* W; const float* bias; float* C; int col0;
  if constexpr (MODE == 0) {
    int wsel = cg0 >> 9; col0 = cg0 & 511;
    W    = wsel == 0 ? Wa : (wsel == 1 ? Wb : Wc);
    bias = wsel == 0 ? ba : (wsel == 1 ? bb : bc);
    C    = wsel == 0 ? Ca : (wsel == 1 ? Cb : Cc);
  } else {
    W = Wa; bias = ba; C = Ca; col0 = cg0;
  }

  const int lane = tid & 63;
  const int w    = tid >> 6;
  const int wr   = (w >> 1) * 64;
  const int wc   = (w & 1) * 32;
  const int frow = lane & 15;
  const int fk   = (lane >> 4) * 8;

  f32x4 acc[4][2];
#pragma unroll
  for (int a = 0; a < 4; ++a)
#pragma unroll
    for (int b = 0; b < 2; ++b) acc[a][b] = (f32x4){0.f, 0.f, 0.f, 0.f};

  for (int k0 = 0; k0 < 512; k0 += 32) {
    // ---- stage A
    if constexpr (MODE != 1) {
      int c = tid & 3, rA = tid >> 2;
#pragma unroll
      for (int m = 0; m < 2; ++m) {
        int rr = rA + m * 64;
        long gi = (long)(row0 + rr) * 512 + k0 + c * 8;
        *(us8v*)&Ah[rr][c * 8] = *(const us8v*)&Aph[gi];
        *(us8v*)&Al[rr][c * 8] = *(const us8v*)&Apl[gi];
      }
    } else {
      int kq = tid & 7, r8 = tid >> 3;
#pragma unroll
      for (int m = 0; m < 4; ++m) {
        int rr = r8 + m * 32;
        int gr = min(row0 + rr, L_ - 1);   // clamp; garbage rows never stored
        float4 a = *(const float4*)&Afp[(long)gr * 512 + k0 + kq * 4];
        us4v h, l; unsigned short th, tl;
        split_bf16(a.x, th, tl); h[0] = th; l[0] = tl;
        split_bf16(a.y, th, tl); h[1] = th; l[1] = tl;
        split_bf16(a.z, th, tl); h[2] = th; l[2] = tl;
        split_bf16(a.w, th, tl); h[3] = th; l[3] = tl;
        *(us4v*)&Ah[rr][kq * 4] = h;
        *(us4v*)&Al[rr][kq * 4] = l;
      }
    }
    // ---- stage B (on-the-fly split of W)
    {
      int colB = tid & 63, kg = tid >> 6;
      us8v h, l;
#pragma unroll
      for (int j = 0; j < 8; ++j) {
        float wv = W[(long)(k0 + kg * 8 + j) * 512 + col0 + colB];
        unsigned short th, tl;
        split_bf16(wv, th, tl);
        h[j] = th; l[j] = tl;
      }
      *(us8v*)&Bh[colB][kg * 8] = h;
      *(us8v*)&Bl[colB][kg * 8] = l;
    }
    __syncthreads();

    bf16x8 ah[4], al[4], bh[2], bl[2];
#pragma unroll
    for (int a = 0; a < 4; ++a) {
      ah[a] = *(const bf16x8*)&Ah[wr + a * 16 + frow][fk];
      al[a] = *(const bf16x8*)&Al[wr + a * 16 + frow][fk];
    }
#pragma unroll
    for (int b = 0; b < 2; ++b) {
      bh[b] = *(const bf16x8*)&Bh[wc + b * 16 + frow][fk];
      bl[b] = *(const bf16x8*)&Bl[wc + b * 16 + frow][fk];
    }
#pragma unroll
    for (int a = 0; a < 4; ++a)
#pragma unroll
      for (int b = 0; b < 2; ++b) {
        acc[a][b] = __builtin_amdgcn_mfma_f32_16x16x32_bf16(ah[a], bh[b], acc[a][b], 0, 0, 0);
        acc[a][b] = __builtin_amdgcn_mfma_f32_16x16x32_bf16(ah[a], bl[b], acc[a][b], 0, 0, 0);
        acc[a][b] = __builtin_amdgcn_mfma_f32_16x16x32_bf16(al[a], bh[b], acc[a][b], 0, 0, 0);
      }
    __syncthreads();
  }

  // ---- epilogue: D col = lane&15, row = (lane>>4)*4 + reg
#pragma unroll
  for (int b = 0; b < 2; ++b) {
    int col = col0 + wc + b * 16 + frow;
    float bv = bias ? bias[col] : 0.f;
#pragma unroll
    for (int a = 0; a < 4; ++a) {
      int rbase = row0 + wr + a * 16 + (lane >> 4) * 4;
#pragma unroll
      for (int g = 0; g < 4; ++g) {
        int row = rbase + g;
        if (MODE == 1 && row >= L_) continue;
        C[(long)row * 512 + col] = acc[a][b][g] + bv;
      }
    }
  }
}

// ---------------------------------------------------------------------------
// Fused relative-position attention, fp32 VALU, XOR-swizzled LDS columns.
// swz(d) = ((d>>2)&7)<<2 keeps 16B alignment, breaks the 8-way staging-store
// conflicts down to ~2-way. PT written as float4 with its own swizzle.
// Epilogue emits the attn output directly as bf16 hi/lo pairs for the O GEMM.
// ---------------------------------------------------------------------------
__global__ __launch_bounds__(512)
void attn_fused_kernel(const float* __restrict__ qm, const float* __restrict__ km,
                       const float* __restrict__ vm, const float* __restrict__ rm,
                       const float* __restrict__ ub, const float* __restrict__ vb,
                       unsigned short* __restrict__ oh, unsigned short* __restrict__ ol) {
  const int qt = blockIdx.x;
  const int h  = blockIdx.y;
  const int b  = blockIdx.z;
  const int q0 = qt * TQ;
  const int tid = threadIdx.x;
  const int tx = tid & 15;
  const int ty = tid >> 4;

  __shared__ float QuT[64][TQ + 4];   // [d][qi^swz(d)]
  __shared__ float RW[64][200];       // [d][g^swz(d)]
  __shared__ float KT[64][TJ + 4];    // [d][ji^swz(d)]
  __shared__ float Vs[TJ][DH_ + 4];   // [ji][d]
  __shared__ float dvu[64];
  float (*PT)[TQ + 4] = (float (*)[TQ + 4])&RW[0][0];  // alias: [ji][qi^swzP(ji)]

#define SWZ(d)  ((((d) >> 2) & 7) << 2)

  if (tid < 64) dvu[tid] = vb[h * DH_ + tid] - ub[h * DH_ + tid];

#pragma unroll
  for (int s = tid; s < TQ * 16; s += 512) {
    int qi = s >> 4;
    int d4 = (s & 15) << 2;
    float4 a  = *(const float4*)&qm[(long)(b * T_ + q0 + qi) * D_ + h * DH_ + d4];
    float4 uu = *(const float4*)&ub[h * DH_ + d4];
    QuT[d4 + 0][qi ^ SWZ(d4 + 0)] = a.x + uu.x;
    QuT[d4 + 1][qi ^ SWZ(d4 + 1)] = a.y + uu.y;
    QuT[d4 + 2][qi ^ SWZ(d4 + 2)] = a.z + uu.z;
    QuT[d4 + 3][qi ^ SWZ(d4 + 3)] = a.w + uu.w;
  }

  float acc[4][4];
#pragma unroll
  for (int i = 0; i < 4; ++i)
#pragma unroll
    for (int j = 0; j < 4; ++j) acc[i][j] = 0.f;
  float m_run[4], l_run[4];
#pragma unroll
  for (int i = 0; i < 4; ++i) { m_run[i] = -3.0e38f; l_run[i] = 0.f; }

  for (int j0 = 0; j0 < T_; j0 += TJ) {
    __syncthreads();

#pragma unroll
    for (int s = tid; s < TJ * 16; s += 512) {
      int ji = s >> 4;
      int d4 = (s & 15) << 2;
      float4 a = *(const float4*)&km[(long)(b * T_ + j0 + ji) * D_ + h * DH_ + d4];
      KT[d4 + 0][ji ^ SWZ(d4 + 0)] = a.x;
      KT[d4 + 1][ji ^ SWZ(d4 + 1)] = a.y;
      KT[d4 + 2][ji ^ SWZ(d4 + 2)] = a.z;
      KT[d4 + 3][ji ^ SWZ(d4 + 3)] = a.w;
    }
#pragma unroll
    for (int s = tid; s < TJ * 16; s += 512) {
      int ji = s >> 4;
      int d4 = (s & 15) << 2;
      *(float4*)&Vs[ji][d4] = *(const float4*)&vm[(long)(b * T_ + j0 + ji) * D_ + h * DH_ + d4];
    }
    const int w0 = j0 - q0 + (T_ - 1) - (TQ - 1);
#pragma unroll
    for (int s = tid; s < 192 * 16; s += 512) {
      int g  = s >> 4;
      int d4 = (s & 15) << 2;
      int ww = w0 + g;
      ww = min(max(ww, 0), L_ - 1);
      float4 a = *(const float4*)&rm[(long)ww * D_ + h * DH_ + d4];
      RW[d4 + 0][g ^ SWZ(d4 + 0)] = a.x;
      RW[d4 + 1][g ^ SWZ(d4 + 1)] = a.y;
      RW[d4 + 2][g ^ SWZ(d4 + 2)] = a.z;
      RW[d4 + 3][g ^ SWZ(d4 + 3)] = a.w;
    }
    __syncthreads();

    float ac[4][4], bd[4][4];
#pragma unroll
    for (int i = 0; i < 4; ++i)
#pragma unroll
      for (int j = 0; j < 4; ++j) { ac[i][j] = 0.f; bd[i][j] = 0.f; }

    const int c0 = (TQ - 4) + 4 * tx - 4 * ty;
    for (int d = 0; d < 64; ++d) {
      const int sw = SWZ(d);
      float4 qu4 = *(const float4*)&QuT[d][(ty << 2) ^ sw];
      float4 k4  = *(const float4*)&KT[d][(tx << 2) ^ sw];
      float4 ra  = *(const float4*)&RW[d][c0 ^ sw];
      float4 rb  = *(const float4*)&RW[d][(c0 + 4) ^ sw];
      float dv = dvu[d];
      float qa[4] = {qu4.x, qu4.y, qu4.z, qu4.w};
      float ka[4] = {k4.x, k4.y, k4.z, k4.w};
      float rt[8] = {ra.x, ra.y, ra.z, ra.w, rb.x, rb.y, rb.z, rb.w};
#pragma unroll
      for (int i = 0; i < 4; ++i) {
        float qv = qa[i] + dv;
#pragma unroll
        for (int j = 0; j < 4; ++j) {
          ac[i][j] = fmaf(qa[i], ka[j], ac[i][j]);
          bd[i][j] = fmaf(qv, rt[j - i + 3], bd[i][j]);
        }
      }
    }

    float p[4][4];
#pragma unroll
    for (int i = 0; i < 4; ++i)
#pragma unroll
      for (int j = 0; j < 4; ++j)
        p[i][j] = (ac[i][j] + bd[i][j]) * 0.125f;

#pragma unroll
    for (int i = 0; i < 4; ++i) {
      float lm = fmaxf(fmaxf(p[i][0], p[i][1]), fmaxf(p[i][2], p[i][3]));
#pragma unroll
      for (int off = 1; off < 16; off <<= 1)
        lm = fmaxf(lm, __shfl_xor(lm, off, 64));
      float mnew = fmaxf(m_run[i], lm);
      float sc = __expf(m_run[i] - mnew);
      float srow = 0.f;
#pragma unroll
      for (int j = 0; j < 4; ++j) {
        p[i][j] = __expf(p[i][j] - mnew);
        srow += p[i][j];
      }
#pragma unroll
      for (int off = 1; off < 16; off <<= 1)
        srow += __shfl_xor(srow, off, 64);
      l_run[i] = l_run[i] * sc + srow;
      m_run[i] = mnew;
#pragma unroll
      for (int j = 0; j < 4; ++j) acc[i][j] *= sc;
    }

    __syncthreads();
#pragma unroll
    for (int j = 0; j < 4; ++j) {
      int rowp = (tx << 2) + j;
      float4 pv = make_float4(p[0][j], p[1][j], p[2][j], p[3][j]);
      *(float4*)&PT[rowp][(ty << 2) ^ SWZ(rowp)] = pv;
    }
    __syncthreads();

    for (int ji = 0; ji < TJ; ++ji) {
      float4 p4 = *(const float4*)&PT[ji][(ty << 2) ^ SWZ(ji)];
      float4 v4 = *(const float4*)&Vs[ji][tx << 2];
      float pa[4] = {p4.x, p4.y, p4.z, p4.w};
      float va[4] = {v4.x, v4.y, v4.z, v4.w};
#pragma unroll
      for (int i = 0; i < 4; ++i)
#pragma unroll
        for (int j = 0; j < 4; ++j)
          acc[i][j] = fmaf(pa[i], va[j], acc[i][j]);
    }
  }

  // epilogue: normalize, split to bf16 hi/lo, store [B,T,H,DH]
#pragma unroll
  for (int i = 0; i < 4; ++i) {
    float inv = 1.f / l_run[i];
    long idx = (long)(b * T_ + q0 + (ty << 2) + i) * D_ + h * DH_ + (tx << 2);
    us4v hv, lv;
#pragma unroll
    for (int j = 0; j < 4; ++j) {
      unsigned short th, tl;
      split_bf16(acc[i][j] * inv, th, tl);
      hv[j] = th; lv[j] = tl;
    }
    *(us4v*)&oh[idx] = hv;
    *(us4v*)&ol[idx] = lv;
  }
#undef SWZ
}

// ---------------------------------------------------------------------------
extern "C" void kernel_launch(void* const* d_in, const int* in_sizes, int n_in,
                              void* d_out, int out_size, void* d_ws, size_t ws_size,
                              hipStream_t stream) {
  const float* x       = (const float*)d_in[0];
  const float* pos_emb = (const float*)d_in[1];
  const float* Wq      = (const float*)d_in[2];
  const float* bq      = (const float*)d_in[3];
  const float* Wk      = (const float*)d_in[4];
  const float* bk      = (const float*)d_in[5];
  const float* Wv      = (const float*)d_in[6];
  const float* bv      = (const float*)d_in[7];
  const float* Wr      = (const float*)d_in[8];
  const float* Wo      = (const float*)d_in[9];
  const float* bo      = (const float*)d_in[10];
  const float* ub      = (const float*)d_in[11];
  const float* vbias   = (const float*)d_in[12];

  float* out = (float*)d_out;
  const int MT = B_ * T_;                       // 4096

  // ws layout (36 MB total, same footprint as round 1):
  float* q  = (float*)d_ws;                     // [4096,512] fp32  8MB
  float* k  = q  + (long)MT * D_;               // [4096,512] fp32  8MB
  float* vv = k  + (long)MT * D_;               // [4096,512] fp32  8MB
  float* r  = vv + (long)MT * D_;               // [2048,512] fp32  4MB
  unsigned short* xh = (unsigned short*)(r + 2048L * D_);  // [4096,512] bf16 4MB
  unsigned short* xl = xh + (long)MT * D_;                 // [4096,512] bf16 4MB
  // after the QKV GEMM consumes xh/xl, attn reuses them as att hi/lo:
  unsigned short* atth = xh;
  unsigned short* attl = xl;

  convert_split<<<2048, 256, 0, stream>>>(x, xh, xl);
  gemm_split<0><<<dim3(32, 24), 256, 0, stream>>>(xh, xl, nullptr,
                                                  Wq, Wk, Wv, bq, bk, bv, q, k, vv);
  gemm_split<1><<<dim3(16, 8), 256, 0, stream>>>(nullptr, nullptr, pos_emb,
                                                 Wr, nullptr, nullptr,
                                                 nullptr, nullptr, nullptr,
                                                 r, nullptr, nullptr);
  attn_fused_kernel<<<dim3(T_ / TQ, H_, B_), 512, 0, stream>>>(q, k, vv, r, ub, vbias, atth, attl);
  gemm_split<2><<<dim3(32, 8), 256, 0, stream>>>(atth, attl, nullptr,
                                                 Wo, nullptr, nullptr,
                                                 bo, nullptr, nullptr,
                                                 out, nullptr, nullptr);
}

// Round 3
// 299.786 us; speedup vs baseline: 1.8294x; 1.3305x over previous
//
#include <hip/hip_runtime.h>

#define B_ 4
#define T_ 1024
#define D_ 512
#define H_ 8
#define DH_ 64
#define L_ 2047

#define TQ 128
#define TJ 64

typedef __attribute__((ext_vector_type(8))) short bf16x8;
typedef __attribute__((ext_vector_type(4))) float f32x4;
typedef __attribute__((ext_vector_type(8))) unsigned short us8v;
typedef __attribute__((ext_vector_type(4))) unsigned short us4v;

struct GemmOut { float* f; unsigned short* h; unsigned short* l; };

__device__ __forceinline__ void split_bf16(float a, unsigned short& h, unsigned short& l) {
  unsigned u = __float_as_uint(a);
  h = (unsigned short)(u >> 16);
  float hf = __uint_as_float(u & 0xFFFF0000u);
  l = (unsigned short)(__float_as_uint(a - hf) >> 16);
}

// ---------------------------------------------------------------------------
// x -> (hi, lo) bf16 split, elementwise.
// ---------------------------------------------------------------------------
__global__ __launch_bounds__(256)
void convert_split(const float* __restrict__ in, unsigned short* __restrict__ hi,
                   unsigned short* __restrict__ lo) {
  int i = (blockIdx.x * 256 + threadIdx.x) * 4;
  float4 a = *(const float4*)&in[i];
  us4v h, l;
  unsigned short th, tl;
  split_bf16(a.x, th, tl); h[0] = th; l[0] = tl;
  split_bf16(a.y, th, tl); h[1] = th; l[1] = tl;
  split_bf16(a.z, th, tl); h[2] = th; l[2] = tl;
  split_bf16(a.w, th, tl); h[3] = th; l[3] = tl;
  *(us4v*)&hi[i] = h;
  *(us4v*)&lo[i] = l;
}

// ---------------------------------------------------------------------------
// Split-bf16 MFMA GEMM: C[M,512] = A[M,512] @ W[512,512] (+bias).
// Epilogue per output: fp32 (O.f) or split-bf16 pair (O.h/O.l).
// ---------------------------------------------------------------------------
template<int MODE>
__global__ __launch_bounds__(256)
void gemm_split(const unsigned short* __restrict__ Aph, const unsigned short* __restrict__ Apl,
                const float* __restrict__ Afp,
                const float* __restrict__ Wa, const float* __restrict__ Wb, const float* __restrict__ Wc,
                const float* __restrict__ ba, const float* __restrict__ bb, const float* __restrict__ bc,
                GemmOut oa, GemmOut ob, GemmOut oc) {
  __shared__ unsigned short Ah[128][40], Al[128][40];
  __shared__ unsigned short Bh[64][40],  Bl[64][40];

  const int tid = threadIdx.x;
  const int row0 = blockIdx.x * 128;
  const int cg0  = blockIdx.y * 64;

  const float* W; const float* bias; GemmOut O; int col0;
  if constexpr (MODE == 0) {
    int wsel = cg0 >> 9; col0 = cg0 & 511;
    W    = wsel == 0 ? Wa : (wsel == 1 ? Wb : Wc);
    bias = wsel == 0 ? ba : (wsel == 1 ? bb : bc);
    O    = wsel == 0 ? oa : (wsel == 1 ? ob : oc);
  } else {
    W = Wa; bias = ba; O = oa; col0 = cg0;
  }

  const int lane = tid & 63;
  const int w    = tid >> 6;
  const int wr   = (w >> 1) * 64;
  const int wc   = (w & 1) * 32;
  const int frow = lane & 15;
  const int fk   = (lane >> 4) * 8;

  f32x4 acc[4][2];
#pragma unroll
  for (int a = 0; a < 4; ++a)
#pragma unroll
    for (int b = 0; b < 2; ++b) acc[a][b] = (f32x4){0.f, 0.f, 0.f, 0.f};

  for (int k0 = 0; k0 < 512; k0 += 32) {
    if constexpr (MODE != 1) {
      int c = tid & 3, rA = tid >> 2;
#pragma unroll
      for (int m = 0; m < 2; ++m) {
        int rr = rA + m * 64;
        long gi = (long)(row0 + rr) * 512 + k0 + c * 8;
        *(us8v*)&Ah[rr][c * 8] = *(const us8v*)&Aph[gi];
        *(us8v*)&Al[rr][c * 8] = *(const us8v*)&Apl[gi];
      }
    } else {
      int kq = tid & 7, r8 = tid >> 3;
#pragma unroll
      for (int m = 0; m < 4; ++m) {
        int rr = r8 + m * 32;
        int gr = min(row0 + rr, L_ - 1);
        float4 a = *(const float4*)&Afp[(long)gr * 512 + k0 + kq * 4];
        us4v h, l; unsigned short th, tl;
        split_bf16(a.x, th, tl); h[0] = th; l[0] = tl;
        split_bf16(a.y, th, tl); h[1] = th; l[1] = tl;
        split_bf16(a.z, th, tl); h[2] = th; l[2] = tl;
        split_bf16(a.w, th, tl); h[3] = th; l[3] = tl;
        *(us4v*)&Ah[rr][kq * 4] = h;
        *(us4v*)&Al[rr][kq * 4] = l;
      }
    }
    {
      int colB = tid & 63, kg = tid >> 6;
      us8v h, l;
#pragma unroll
      for (int j = 0; j < 8; ++j) {
        float wv = W[(long)(k0 + kg * 8 + j) * 512 + col0 + colB];
        unsigned short th, tl;
        split_bf16(wv, th, tl);
        h[j] = th; l[j] = tl;
      }
      *(us8v*)&Bh[colB][kg * 8] = h;
      *(us8v*)&Bl[colB][kg * 8] = l;
    }
    __syncthreads();

    bf16x8 ah[4], al[4], bh[2], bl[2];
#pragma unroll
    for (int a = 0; a < 4; ++a) {
      ah[a] = *(const bf16x8*)&Ah[wr + a * 16 + frow][fk];
      al[a] = *(const bf16x8*)&Al[wr + a * 16 + frow][fk];
    }
#pragma unroll
    for (int b = 0; b < 2; ++b) {
      bh[b] = *(const bf16x8*)&Bh[wc + b * 16 + frow][fk];
      bl[b] = *(const bf16x8*)&Bl[wc + b * 16 + frow][fk];
    }
#pragma unroll
    for (int a = 0; a < 4; ++a)
#pragma unroll
      for (int b = 0; b < 2; ++b) {
        acc[a][b] = __builtin_amdgcn_mfma_f32_16x16x32_bf16(ah[a], bh[b], acc[a][b], 0, 0, 0);
        acc[a][b] = __builtin_amdgcn_mfma_f32_16x16x32_bf16(ah[a], bl[b], acc[a][b], 0, 0, 0);
        acc[a][b] = __builtin_amdgcn_mfma_f32_16x16x32_bf16(al[a], bh[b], acc[a][b], 0, 0, 0);
      }
    __syncthreads();
  }

#pragma unroll
  for (int b = 0; b < 2; ++b) {
    int col = col0 + wc + b * 16 + frow;
    float bv = bias ? bias[col] : 0.f;
#pragma unroll
    for (int a = 0; a < 4; ++a) {
      int rbase = row0 + wr + a * 16 + (lane >> 4) * 4;
#pragma unroll
      for (int g = 0; g < 4; ++g) {
        int row = rbase + g;
        if (MODE == 1 && row >= L_) continue;
        long idx = (long)row * 512 + col;
        float val = acc[a][b][g] + bv;
        if (O.f) O.f[idx] = val;
        else {
          unsigned short th, tl;
          split_bf16(val, th, tl);
          O.h[idx] = th; O.l[idx] = tl;
        }
      }
    }
  }
}

// ---------------------------------------------------------------------------
// Fused relative-position attention, split-bf16 MFMA.
// Block = (q-tile 128, head, batch), 512 thr = 8 waves, wave owns 16 q-rows.
// Per j-tile (64): AC = Qu·K^T (MFMA), BD' = Qv·RW^T over a per-wave 80-col
// diagonal band (MFMA), band -> wave-private LDS, shifted gather, online
// softmax, P split -> LDS, PV = P·V (MFMA).
// ---------------------------------------------------------------------------
__global__ __launch_bounds__(512)
void attn_mfma_kernel(const float* __restrict__ qm,
                      const unsigned short* __restrict__ kh, const unsigned short* __restrict__ kl,
                      const unsigned short* __restrict__ vh, const unsigned short* __restrict__ vl,
                      const unsigned short* __restrict__ rh, const unsigned short* __restrict__ rl,
                      const float* __restrict__ ub, const float* __restrict__ vbias,
                      unsigned short* __restrict__ oh, unsigned short* __restrict__ ol) {
  const int qt = blockIdx.x, h = blockIdx.y, b = blockIdx.z;
  const int q0 = qt * TQ;
  const int tid = threadIdx.x;
  const int lane = tid & 63;
  const int wid = tid >> 6;     // 0..7, wave owns rows [wid*16, wid*16+16)
  const int lr = lane & 15;
  const int lg = lane >> 4;     // 0..3

  __shared__ union {
    struct {
      unsigned short Kh[64][72], Kl[64][72];
      unsigned short RWh[192][72], RWl[192][72];
    } s;
    float bd[8][16][84];        // per-wave BD' band [rowl][band-col]
  } RA;
  __shared__ unsigned short Vh[64][72], Vl[64][72];   // [d][ji]
  __shared__ unsigned short Ph[128][72], Pl[128][72]; // [qi][ji]

  // ---- A-fragments (once): Qu = q+u, Qv = q+v, split, frag layout
  // row = lr (q-row within wave band), k = lg*8 + j (+32*ks)
  bf16x8 quh[2], qul[2], qvh[2], qvl[2];
  {
    const long qrow = (long)(b * T_ + q0 + wid * 16 + lr);
#pragma unroll
    for (int ks = 0; ks < 2; ++ks) {
      const float* qp = qm + qrow * 512 + h * 64 + ks * 32 + lg * 8;
      float4 a0 = *(const float4*)qp;
      float4 a1 = *(const float4*)(qp + 4);
      const float* up = ub + h * 64 + ks * 32 + lg * 8;
      float4 u0 = *(const float4*)up, u1 = *(const float4*)(up + 4);
      const float* vp = vbias + h * 64 + ks * 32 + lg * 8;
      float4 v0 = *(const float4*)vp, v1 = *(const float4*)(vp + 4);
      float qa[8] = {a0.x, a0.y, a0.z, a0.w, a1.x, a1.y, a1.z, a1.w};
      float ua[8] = {u0.x, u0.y, u0.z, u0.w, u1.x, u1.y, u1.z, u1.w};
      float va[8] = {v0.x, v0.y, v0.z, v0.w, v1.x, v1.y, v1.z, v1.w};
#pragma unroll
      for (int e = 0; e < 8; ++e) {
        unsigned short th, tl;
        split_bf16(qa[e] + ua[e], th, tl);
        quh[ks][e] = (short)th; qul[ks][e] = (short)tl;
        split_bf16(qa[e] + va[e], th, tl);
        qvh[ks][e] = (short)th; qvl[ks][e] = (short)tl;
      }
    }
  }

  f32x4 pv[4];
#pragma unroll
  for (int c = 0; c < 4; ++c) pv[c] = (f32x4){0.f, 0.f, 0.f, 0.f};
  float m_run[4], l_run[4];
#pragma unroll
  for (int r = 0; r < 4; ++r) { m_run[r] = -3.0e38f; l_run[r] = 0.f; }

  const int band0 = 112 - wid * 16;   // wave's BD window base in [0,192)

  for (int j0 = 0; j0 < T_; j0 += TJ) {
    __syncthreads();   // prev-iter LDS reads done; safe to restage

    // ---- stage K [ji][d] (natural)
    {
      int ji = tid >> 3, dg = (tid & 7) * 8;
      long gi = (long)(b * T_ + j0 + ji) * 512 + h * 64 + dg;
      *(us8v*)&RA.s.Kh[ji][dg] = *(const us8v*)&kh[gi];
      *(us8v*)&RA.s.Kl[ji][dg] = *(const us8v*)&kl[gi];
    }
    // ---- stage RW [g][d] (natural), rows w0+g, g in [0,192)
    {
      const int w0 = j0 - q0 + 896;
#pragma unroll
      for (int m = 0; m < 3; ++m) {
        int s = tid + 512 * m;
        int g = s >> 3, dg = (s & 7) * 8;
        int wr_ = min(w0 + g, L_ - 1);   // g=191 garbage-guard (unused output)
        long gi = (long)wr_ * 512 + h * 64 + dg;
        *(us8v*)&RA.s.RWh[g][dg] = *(const us8v*)&rh[gi];
        *(us8v*)&RA.s.RWl[g][dg] = *(const us8v*)&rl[gi];
      }
    }
    // ---- stage V transposed [d][ji], rotated stores (2-way banks)
    {
      int ji = tid >> 3, dgq = tid & 7, dg = dgq * 8;
      long gi = (long)(b * T_ + j0 + ji) * 512 + h * 64 + dg;
      us8v v8h = *(const us8v*)&vh[gi];
      us8v v8l = *(const us8v*)&vl[gi];
#pragma unroll
      for (int t = 0; t < 8; ++t) {
        int e = (t + dgq + ji) & 7;
        Vh[dg + e][ji] = v8h[e];
        Vl[dg + e][ji] = v8l[e];
      }
    }
    __syncthreads();

    // ---- AC + BD' MFMAs
    f32x4 ac[4], bda[5];
#pragma unroll
    for (int c = 0; c < 4; ++c) ac[c] = (f32x4){0.f, 0.f, 0.f, 0.f};
#pragma unroll
    for (int c = 0; c < 5; ++c) bda[c] = (f32x4){0.f, 0.f, 0.f, 0.f};

#pragma unroll
    for (int ks = 0; ks < 2; ++ks) {
#pragma unroll
      for (int c = 0; c < 4; ++c) {
        bf16x8 kbh = *(const bf16x8*)&RA.s.Kh[c * 16 + lr][ks * 32 + lg * 8];
        bf16x8 kbl = *(const bf16x8*)&RA.s.Kl[c * 16 + lr][ks * 32 + lg * 8];
        ac[c] = __builtin_amdgcn_mfma_f32_16x16x32_bf16(quh[ks], kbh, ac[c], 0, 0, 0);
        ac[c] = __builtin_amdgcn_mfma_f32_16x16x32_bf16(quh[ks], kbl, ac[c], 0, 0, 0);
        ac[c] = __builtin_amdgcn_mfma_f32_16x16x32_bf16(qul[ks], kbh, ac[c], 0, 0, 0);
      }
#pragma unroll
      for (int c = 0; c < 5; ++c) {
        bf16x8 rbh = *(const bf16x8*)&RA.s.RWh[band0 + c * 16 + lr][ks * 32 + lg * 8];
        bf16x8 rbl = *(const bf16x8*)&RA.s.RWl[band0 + c * 16 + lr][ks * 32 + lg * 8];
        bda[c] = __builtin_amdgcn_mfma_f32_16x16x32_bf16(qvh[ks], rbh, bda[c], 0, 0, 0);
        bda[c] = __builtin_amdgcn_mfma_f32_16x16x32_bf16(qvh[ks], rbl, bda[c], 0, 0, 0);
        bda[c] = __builtin_amdgcn_mfma_f32_16x16x32_bf16(qvl[ks], rbh, bda[c], 0, 0, 0);
      }
    }
    __syncthreads();   // all K/RW frag reads done before BD band overwrite

    // ---- BD band -> wave-private LDS (C layout: row=lg*4+r, col=c*16+lr)
#pragma unroll
    for (int c = 0; c < 5; ++c)
#pragma unroll
      for (int r = 0; r < 4; ++r)
        RA.bd[wid][lg * 4 + r][c * 16 + lr] = bda[c][r];

    // ---- shifted gather + scores
    float s_[4][4];
#pragma unroll
    for (int c = 0; c < 4; ++c)
#pragma unroll
      for (int r = 0; r < 4; ++r) {
        int rowl = lg * 4 + r;
        float bdv = RA.bd[wid][rowl][(c * 16 + lr) - rowl + 15];
        s_[c][r] = (ac[c][r] + bdv) * 0.125f;
      }

    // ---- online softmax (rows rowl; 16-lane groups hold the 64 cols)
#pragma unroll
    for (int r = 0; r < 4; ++r) {
      float lm = fmaxf(fmaxf(s_[0][r], s_[1][r]), fmaxf(s_[2][r], s_[3][r]));
#pragma unroll
      for (int off = 1; off < 16; off <<= 1)
        lm = fmaxf(lm, __shfl_xor(lm, off));
      float mnew = fmaxf(m_run[r], lm);
      float rescale = __expf(m_run[r] - mnew);
      float srow = 0.f;
#pragma unroll
      for (int c = 0; c < 4; ++c) {
        float p = __expf(s_[c][r] - mnew);
        s_[c][r] = p;
        srow += p;
      }
#pragma unroll
      for (int off = 1; off < 16; off <<= 1)
        srow += __shfl_xor(srow, off);
      l_run[r] = l_run[r] * rescale + srow;
      m_run[r] = mnew;
#pragma unroll
      for (int c = 0; c < 4; ++c) pv[c][r] *= rescale;
    }

    // ---- P split -> LDS (wave-private rows)
#pragma unroll
    for (int c = 0; c < 4; ++c)
#pragma unroll
      for (int r = 0; r < 4; ++r) {
        unsigned short th, tl;
        split_bf16(s_[c][r], th, tl);
        Ph[wid * 16 + lg * 4 + r][c * 16 + lr] = th;
        Pl[wid * 16 + lg * 4 + r][c * 16 + lr] = tl;
      }

    // ---- PV MFMAs (P wave-private; V staged this iter)
#pragma unroll
    for (int ks = 0; ks < 2; ++ks) {
      bf16x8 pah = *(const bf16x8*)&Ph[wid * 16 + lr][ks * 32 + lg * 8];
      bf16x8 pal = *(const bf16x8*)&Pl[wid * 16 + lr][ks * 32 + lg * 8];
#pragma unroll
      for (int c = 0; c < 4; ++c) {
        bf16x8 vb_h = *(const bf16x8*)&Vh[c * 16 + lr][ks * 32 + lg * 8];
        bf16x8 vb_l = *(const bf16x8*)&Vl[c * 16 + lr][ks * 32 + lg * 8];
        pv[c] = __builtin_amdgcn_mfma_f32_16x16x32_bf16(pah, vb_h, pv[c], 0, 0, 0);
        pv[c] = __builtin_amdgcn_mfma_f32_16x16x32_bf16(pah, vb_l, pv[c], 0, 0, 0);
        pv[c] = __builtin_amdgcn_mfma_f32_16x16x32_bf16(pal, vb_h, pv[c], 0, 0, 0);
      }
    }
  }

  // ---- epilogue: normalize, split, store [B,T,H,DH] as hi/lo bf16
#pragma unroll
  for (int r = 0; r < 4; ++r) {
    float inv = 1.f / l_run[r];
    long base = (long)(b * T_ + q0 + wid * 16 + lg * 4 + r) * 512 + h * 64;
#pragma unroll
    for (int c = 0; c < 4; ++c) {
      unsigned short th, tl;
      split_bf16(pv[c][r] * inv, th, tl);
      oh[base + c * 16 + lr] = th;
      ol[base + c * 16 + lr] = tl;
    }
  }
}

// ---------------------------------------------------------------------------
extern "C" void kernel_launch(void* const* d_in, const int* in_sizes, int n_in,
                              void* d_out, int out_size, void* d_ws, size_t ws_size,
                              hipStream_t stream) {
  const float* x       = (const float*)d_in[0];
  const float* pos_emb = (const float*)d_in[1];
  const float* Wq      = (const float*)d_in[2];
  const float* bq      = (const float*)d_in[3];
  const float* Wk      = (const float*)d_in[4];
  const float* bk      = (const float*)d_in[5];
  const float* Wv      = (const float*)d_in[6];
  const float* bv      = (const float*)d_in[7];
  const float* Wr      = (const float*)d_in[8];
  const float* Wo      = (const float*)d_in[9];
  const float* bo      = (const float*)d_in[10];
  const float* ub      = (const float*)d_in[11];
  const float* vbias   = (const float*)d_in[12];

  float* out = (float*)d_out;
  const long MT = (long)B_ * T_;   // 4096

  // ws layout (36 MB, same footprint as rounds 1-2):
  float* q = (float*)d_ws;                                  // 8 MB fp32
  unsigned short* kh = (unsigned short*)(q + MT * D_);      // 4 MB
  unsigned short* kl = kh + MT * D_;                        // 4 MB
  unsigned short* vh = kl + MT * D_;                        // 4 MB
  unsigned short* vl = vh + MT * D_;                        // 4 MB
  unsigned short* rh = vl + MT * D_;                        // 2 MB (2048 rows)
  unsigned short* rl = rh + 2048L * D_;                     // 2 MB
  unsigned short* xh = rl + 2048L * D_;                     // 4 MB
  unsigned short* xl = xh + MT * D_;                        // 4 MB
  unsigned short* atth = xh;  // reuse after QKV GEMM consumes x
  unsigned short* attl = xl;

  GemmOut oq{q, nullptr, nullptr};
  GemmOut ok{nullptr, kh, kl};
  GemmOut ov{nullptr, vh, vl};
  GemmOut orr{nullptr, rh, rl};
  GemmOut oo{out, nullptr, nullptr};
  GemmOut onull{nullptr, nullptr, nullptr};

  convert_split<<<2048, 256, 0, stream>>>(x, xh, xl);
  gemm_split<0><<<dim3(32, 24), 256, 0, stream>>>(xh, xl, nullptr,
                                                  Wq, Wk, Wv, bq, bk, bv, oq, ok, ov);
  gemm_split<1><<<dim3(16, 8), 256, 0, stream>>>(nullptr, nullptr, pos_emb,
                                                 Wr, nullptr, nullptr,
                                                 nullptr, nullptr, nullptr,
                                                 orr, onull, onull);
  attn_mfma_kernel<<<dim3(T_ / TQ, H_, B_), 512, 0, stream>>>(q, kh, kl, vh, vl, rh, rl,
                                                              ub, vbias, atth, attl);
  gemm_split<2><<<dim3(32, 8), 256, 0, stream>>>(atth, attl, nullptr,
                                                 Wo, nullptr, nullptr,
                                                 bo, nullptr, nullptr,
                                                 oo, onull, onull);
}